// Round 2
// baseline (443.081 us; speedup 1.0000x reference)
//
#include <hip/hip_runtime.h>
#include <hip/hip_bf16.h>
#include <cstdint>

// DistanceAwareSelfAttention: SLEN=1024, BSZ=8, H=16, D=64, EMB=1024, CLIP=10
// Pipeline: f2b converts -> GEMM1 (in_proj, scatter to (3,b,h,s,d)) -> vtrans
//           -> qk band-bias table -> flash attention (+band corrections) -> GEMM2 (out_proj)
// R2: attn loop software-pipelined — V(current) issued at top, K(next) issued
//     right after QK MFMAs; 2x-unrolled body with named A/B K-buffers.

typedef __attribute__((ext_vector_type(8))) __bf16 bf16x8;
typedef __attribute__((ext_vector_type(4))) __bf16 bf16x4;
typedef __attribute__((ext_vector_type(4))) float f32x4;

__device__ __forceinline__ void gload_lds16(const void* g, void* l) {
  __builtin_amdgcn_global_load_lds(
      (const __attribute__((address_space(1))) void*)g,
      (__attribute__((address_space(3))) void*)l, 16, 0, 0);
}

__global__ __launch_bounds__(256) void f2b_kernel(const float* __restrict__ src,
                                                  __bf16* __restrict__ dst, int n) {
  int i = (blockIdx.x * 256 + threadIdx.x) * 8;
  if (i >= n) return;
  float4 a = *(const float4*)(src + i);
  float4 b = *(const float4*)(src + i + 4);
  bf16x8 o;
  o[0] = (__bf16)a.x; o[1] = (__bf16)a.y; o[2] = (__bf16)a.z; o[3] = (__bf16)a.w;
  o[4] = (__bf16)b.x; o[5] = (__bf16)b.y; o[6] = (__bf16)b.z; o[7] = (__bf16)b.w;
  *(bf16x8*)(dst + i) = o;
}

// C[m][n] = sum_k A[m][k]*B[n][k] + bias[n].  128x128 tile, BK=64, 4 waves.
// EPI 0: scatter bf16 to qkvt (3,b,h,s,d), scale q by 0.125.  EPI 1: fp32 out.
template <int EPI>
__global__ __launch_bounds__(256) void gemm_nt(
    const __bf16* __restrict__ A, const __bf16* __restrict__ B,
    const float* __restrict__ bias, int K,
    float* __restrict__ outF, __bf16* __restrict__ outT, int N) {
  __shared__ __align__(16) __bf16 sA[128 * 64];
  __shared__ __align__(16) __bf16 sB[128 * 64];
  const int tid = threadIdx.x;
  const int wave = tid >> 6, lane = tid & 63;
  const int lg = lane >> 4, lr = lane & 15;
  const int wr = wave >> 1, wc = wave & 1;
  const int m0 = blockIdx.y * 128;
  const int n0 = blockIdx.x * 128;

  f32x4 acc[4][4] = {};

  for (int kt = 0; kt < K; kt += 64) {
#pragma unroll
    for (int it = 0; it < 4; ++it) {
      int c = it * 256 + tid;
      int r = c >> 3, c8 = (c & 7) * 8;
      gload_lds16(A + (size_t)(m0 + r) * K + kt + c8,
                  (void*)&sA[(it * 256 + wave * 64) * 8]);
      gload_lds16(B + (size_t)(n0 + r) * K + kt + c8,
                  (void*)&sB[(it * 256 + wave * 64) * 8]);
    }
    __syncthreads();
#pragma unroll
    for (int kk = 0; kk < 2; ++kk) {
      bf16x8 af[4], bfr[4];
#pragma unroll
      for (int i = 0; i < 4; ++i)
        af[i] = *(const bf16x8*)&sA[(wr * 64 + i * 16 + lr) * 64 + kk * 32 + lg * 8];
#pragma unroll
      for (int j = 0; j < 4; ++j)
        bfr[j] = *(const bf16x8*)&sB[(wc * 64 + j * 16 + lr) * 64 + kk * 32 + lg * 8];
#pragma unroll
      for (int i = 0; i < 4; ++i)
#pragma unroll
        for (int j = 0; j < 4; ++j)
          acc[i][j] = __builtin_amdgcn_mfma_f32_16x16x32_bf16(af[i], bfr[j], acc[i][j], 0, 0, 0);
    }
    __syncthreads();
  }

#pragma unroll
  for (int i = 0; i < 4; ++i) {
    const int gm0 = m0 + wr * 64 + i * 16 + lg * 4;
#pragma unroll
    for (int j = 0; j < 4; ++j) {
      const int gn = n0 + wc * 64 + j * 16 + lr;
      const float bv = bias[gn];
#pragma unroll
      for (int rg = 0; rg < 4; ++rg) {
        const int gm = gm0 + rg;
        float v = acc[i][j][rg] + bv;
        if constexpr (EPI == 0) {
          int t = gn >> 10, h = (gn >> 6) & 15, d = gn & 63;
          int s = gm >> 3, b = gm & 7;
          if (t == 0) v *= 0.125f;  // q * d^-0.5
          outT[(((size_t)((t * 8 + b) * 16 + h) * 1024 + s) << 6) + d] = (__bf16)v;
        } else {
          outF[(size_t)gm * N + gn] = v;
        }
      }
    }
  }
}

// v (bh,s,d) -> vt (bh,d,s), 64x64 tiles
__global__ __launch_bounds__(256) void vtrans_kernel(const __bf16* __restrict__ v,
                                                     __bf16* __restrict__ vt) {
  __shared__ __bf16 tile[64][66];
  const int tid = threadIdx.x;
  const int bh = blockIdx.x >> 4;
  const int s0 = (blockIdx.x & 15) * 64;
  const __bf16* src = v + ((size_t)bh * 1024 + s0) * 64;
#pragma unroll
  for (int it = 0; it < 4; ++it) {
    int idx = it * 256 + tid;
    int r = idx >> 4, c4 = (idx & 15) * 4;
    bf16x4 x = *(const bf16x4*)&src[r * 64 + c4];
    tile[r][c4 + 0] = x[0]; tile[r][c4 + 1] = x[1];
    tile[r][c4 + 2] = x[2]; tile[r][c4 + 3] = x[3];
  }
  __syncthreads();
  __bf16* dst = vt + (size_t)bh * 65536;
#pragma unroll
  for (int it = 0; it < 4; ++it) {
    int idx = it * 256 + tid;
    int dr = idx >> 4, s4 = (idx & 15) * 4;
    bf16x4 y;
    y[0] = tile[s4 + 0][dr]; y[1] = tile[s4 + 1][dr];
    y[2] = tile[s4 + 2][dr]; y[3] = tile[s4 + 3][dr];
    *(bf16x4*)&dst[(size_t)dr * 1024 + s0 + s4] = y;
  }
}

// biasD[row][c] = q[row]·(kde[c]-kde[10]) for c<10, else 0.  row = bh*1024+s.
__global__ __launch_bounds__(256) void qkbias_kernel(const __bf16* __restrict__ q,
                                                     const float* __restrict__ kde,
                                                     float* __restrict__ biasD) {
  const int row = blockIdx.x * 16 + (threadIdx.x >> 4);
  const int c = threadIdx.x & 15;
  float acc = 0.f;
  if (c < 10) {
    const __bf16* qr = q + (size_t)row * 64;
#pragma unroll
    for (int d = 0; d < 64; ++d)
      acc += (float)qr[d] * (kde[c * 64 + d] - kde[640 + d]);
  }
  biasD[(size_t)row * 16 + c] = acc;
}

// One flash-attention step for KV-tile KT.  BK = current K regs, BKN = next-tile
// K regs (issued right after QK so its latency hides under softmax+PV).
#define ATTN_STEP(KT, BK, BKN)                                                  \
  {                                                                             \
    const int t0 = (KT) * 64;                                                   \
    /* V loads for current tile: in flight across bias+softmax */               \
    bf16x8 bv[8];                                                               \
    _Pragma("unroll") for (int dj = 0; dj < 4; ++dj) {                          \
      const __bf16* vrow = vtp + (size_t)(dj * 16 + lr) * 1024 + t0 + lg * 8;   \
      bv[dj * 2] = *(const bf16x8*)vrow;                                        \
      bv[dj * 2 + 1] = *(const bf16x8*)(vrow + 32);                             \
    }                                                                           \
    /* QK^T with already-resident K regs */                                     \
    f32x4 sf[4];                                                                \
    _Pragma("unroll") for (int tj = 0; tj < 4; ++tj) {                          \
      f32x4 z = {};                                                             \
      z = __builtin_amdgcn_mfma_f32_16x16x32_bf16(aq[0], BK[tj * 2], z, 0, 0, 0); \
      z = __builtin_amdgcn_mfma_f32_16x16x32_bf16(aq[1], BK[tj * 2 + 1], z, 0, 0, 0); \
      sf[tj] = z;                                                               \
    }                                                                           \
    /* prefetch next tile's K (wraps to 0 on last iter; harmless) */            \
    {                                                                           \
      const int tn = ((KT) + 1) & 15;                                           \
      const __bf16* kbase = kp + (size_t)tn * 4096;                             \
      _Pragma("unroll") for (int tj = 0; tj < 4; ++tj) {                        \
        const __bf16* krow = kbase + (size_t)(tj * 16 + lr) * 64 + lg * 8;      \
        BKN[tj * 2] = *(const bf16x8*)krow;                                     \
        BKN[tj * 2 + 1] = *(const bf16x8*)(krow + 32);                          \
      }                                                                         \
    }                                                                           \
    /* distance-band bias (softmax-invariant shift applied) */                  \
    const bool inband = (t0 <= sb + 24) && (t0 + 63 >= sb - 9);                 \
    if (inband) {                                                               \
      _Pragma("unroll") for (int tj = 0; tj < 4; ++tj) {                        \
        const int t = t0 + tj * 16 + lr;                                        \
        _Pragma("unroll") for (int rg = 0; rg < 4; ++rg) {                      \
          const int s = sb + lg * 4 + rg;                                       \
          const int dd = t - s;                                                 \
          const int ad = dd < 0 ? -dd : dd;                                     \
          const int c = ad < 15 ? ad : 15;                                      \
          const float val = sf[tj][rg] + biasD[((size_t)bh * 1024 + s) * 16 + c]; \
          sf[tj][rg] = val;                                                     \
          if (ad <= 9) band[wave][lg * 4 + rg][dd + 9] = val;                   \
        }                                                                       \
      }                                                                         \
    }                                                                           \
    /* online softmax */                                                        \
    float vmax[4];                                                              \
    _Pragma("unroll") for (int rg = 0; rg < 4; ++rg)                            \
      vmax[rg] = fmaxf(fmaxf(sf[0][rg], sf[1][rg]), fmaxf(sf[2][rg], sf[3][rg])); \
    _Pragma("unroll") for (int off = 1; off < 16; off <<= 1)                    \
      _Pragma("unroll") for (int rg = 0; rg < 4; ++rg)                          \
        vmax[rg] = fmaxf(vmax[rg], __shfl_xor(vmax[rg], off, 64));              \
    float scl[4];                                                               \
    _Pragma("unroll") for (int rg = 0; rg < 4; ++rg) {                          \
      float mn = fmaxf(mrow[rg], vmax[rg]);                                     \
      scl[rg] = __expf(mrow[rg] - mn);                                          \
      mrow[rg] = mn;                                                            \
    }                                                                           \
    float rsum[4] = {0.f, 0.f, 0.f, 0.f};                                       \
    _Pragma("unroll") for (int tj = 0; tj < 4; ++tj)                            \
      _Pragma("unroll") for (int rg = 0; rg < 4; ++rg) {                        \
        float p = __expf(sf[tj][rg] - mrow[rg]);                                \
        sf[tj][rg] = p;                                                         \
        rsum[rg] += p;                                                          \
      }                                                                         \
    _Pragma("unroll") for (int off = 1; off < 16; off <<= 1)                    \
      _Pragma("unroll") for (int rg = 0; rg < 4; ++rg)                          \
        rsum[rg] += __shfl_xor(rsum[rg], off, 64);                              \
    _Pragma("unroll") for (int rg = 0; rg < 4; ++rg)                            \
      lrow[rg] = lrow[rg] * scl[rg] + rsum[rg];                                 \
    _Pragma("unroll") for (int dj = 0; dj < 4; ++dj)                            \
      _Pragma("unroll") for (int rg = 0; rg < 4; ++rg)                          \
        o_acc[dj][rg] *= scl[rg];                                               \
    /* P -> LDS (lane transpose for PV A-operand) */                            \
    _Pragma("unroll") for (int tj = 0; tj < 4; ++tj)                            \
      _Pragma("unroll") for (int rg = 0; rg < 4; ++rg)                          \
        pbuf[wave][lg * 4 + rg][tj * 16 + lr] = (__bf16)sf[tj][rg];             \
    asm volatile("s_waitcnt lgkmcnt(0)" ::: "memory");                          \
    __builtin_amdgcn_sched_barrier(0);                                          \
    /* PV */                                                                    \
    bf16x8 pa[2];                                                               \
    _Pragma("unroll") for (int kk = 0; kk < 2; ++kk)                            \
      pa[kk] = *(const bf16x8*)&pbuf[wave][lr][kk * 32 + lg * 8];               \
    _Pragma("unroll") for (int dj = 0; dj < 4; ++dj) {                          \
      o_acc[dj] = __builtin_amdgcn_mfma_f32_16x16x32_bf16(pa[0], bv[dj * 2], o_acc[dj], 0, 0, 0); \
      o_acc[dj] = __builtin_amdgcn_mfma_f32_16x16x32_bf16(pa[1], bv[dj * 2 + 1], o_acc[dj], 0, 0, 0); \
    }                                                                           \
  }

// Flash attention w/ distance band.  8 waves, 16 q-rows/wave (Q-tile 128), KV tiles of 64.
__global__ __launch_bounds__(512) void attn_kernel(
    const __bf16* __restrict__ qkv, const __bf16* __restrict__ vt,
    const float* __restrict__ biasD, const float* __restrict__ vde,
    __bf16* __restrict__ O) {
  __shared__ float band[8][16][20];            // band logits, slot = (t-s)+9
  __shared__ __align__(16) __bf16 pbuf[8][16][72];  // per-wave P transpose buffer
  const int tid = threadIdx.x, wave = tid >> 6, lane = tid & 63;
  const int lg = lane >> 4, lr = lane & 15;
  const int bh = blockIdx.x >> 3;
  const int stile = blockIdx.x & 7;
  const int sb = stile * 128 + wave * 16;
  const int b = bh >> 4, h = bh & 15;
  const __bf16* qp = qkv + (size_t)bh * 65536;
  const __bf16* kp = qkv + (size_t)(128 + bh) * 65536;
  const __bf16* vtp = vt + (size_t)bh * 65536;

  {
    float* bf = &band[0][0][0];
    for (int i = tid; i < 8 * 16 * 20; i += 512) bf[i] = -1e30f;
  }
  __syncthreads();

  bf16x8 aq[2];
#pragma unroll
  for (int kk = 0; kk < 2; ++kk)
    aq[kk] = *(const bf16x8*)&qp[(size_t)(sb + lr) * 64 + kk * 32 + lg * 8];

  f32x4 o_acc[4] = {};
  float mrow[4], lrow[4];
#pragma unroll
  for (int r = 0; r < 4; ++r) { mrow[r] = -1e30f; lrow[r] = 0.f; }

  // prologue: load K tile 0
  bf16x8 bkA[8], bkB[8];
#pragma unroll
  for (int tj = 0; tj < 4; ++tj) {
    const __bf16* krow = kp + (size_t)(tj * 16 + lr) * 64 + lg * 8;
    bkA[tj * 2] = *(const bf16x8*)krow;
    bkA[tj * 2 + 1] = *(const bf16x8*)(krow + 32);
  }

  for (int kt = 0; kt < 16; kt += 2) {
    ATTN_STEP(kt, bkA, bkB)
    ATTN_STEP(kt + 1, bkB, bkA)
  }

  // ---- epilogue: normalize + v_dist band correction, write (s,b,h*d) bf16 ----
#pragma unroll
  for (int rg = 0; rg < 4; ++rg) {
    const int rl = lg * 4 + rg;
    const int s = sb + rl;
    const float inv = 1.f / lrow[rg];
    float psum[10];
    psum[0] = __expf(band[wave][rl][9] - mrow[rg]);
#pragma unroll
    for (int c = 1; c < 10; ++c)
      psum[c] = __expf(band[wave][rl][9 - c] - mrow[rg]) +
                __expf(band[wave][rl][9 + c] - mrow[rg]);
#pragma unroll
    for (int dj = 0; dj < 4; ++dj) {
      const int d = dj * 16 + lr;
      float acc2 = 0.f;
#pragma unroll
      for (int c = 0; c < 10; ++c)
        acc2 += psum[c] * (vde[c * 64 + d] - vde[640 + d]);
      float val = (o_acc[dj][rg] + acc2) * inv + vde[640 + d];
      O[((size_t)(s * 8 + b)) * 1024 + h * 64 + d] = (__bf16)val;
    }
  }
}

extern "C" void kernel_launch(void* const* d_in, const int* in_sizes, int n_in,
                              void* d_out, int out_size, void* d_ws, size_t ws_size,
                              hipStream_t stream) {
  (void)in_sizes; (void)n_in; (void)out_size; (void)ws_size;
  const float* inputs = (const float*)d_in[0];
  const float* W_in   = (const float*)d_in[1];
  const float* b_in   = (const float*)d_in[2];
  const float* kde    = (const float*)d_in[3];
  const float* vde    = (const float*)d_in[4];
  const float* W_out  = (const float*)d_in[5];
  const float* b_out  = (const float*)d_in[6];
  float* out = (float*)d_out;

  char* ws = (char*)d_ws;
  __bf16* qkvt  = (__bf16*)(ws);              // (3,8,16,1024,64) bf16: 50331648 B
  __bf16* vt    = (__bf16*)(ws + 50331648);   // (128,64,1024)  bf16: 16777216 B
  float*  biasD = (float*) (ws + 67108864);   // (131072,16)    f32:   8388608 B
  __bf16* Xb    = (__bf16*)(ws + 75497472);   // (8192,1024)    bf16: 16777216 B
  __bf16* Ob    = (__bf16*)(ws + 75497472);   // reuse Xb region after GEMM1
  __bf16* Wb_in = (__bf16*)(ws + 92274688);   // (3072,1024)    bf16:  6291456 B
  __bf16* Wb_out= (__bf16*)(ws + 98566144);   // (1024,1024)    bf16:  2097152 B

  f2b_kernel<<<4096, 256, 0, stream>>>(inputs, Xb, 8388608);
  f2b_kernel<<<1536, 256, 0, stream>>>(W_in, Wb_in, 3145728);
  f2b_kernel<<<512, 256, 0, stream>>>(W_out, Wb_out, 1048576);

  gemm_nt<0><<<dim3(24, 64), 256, 0, stream>>>(Xb, Wb_in, b_in, 1024, nullptr, qkvt, 3072);
  vtrans_kernel<<<2048, 256, 0, stream>>>(qkvt + (size_t)2 * 128 * 65536, vt);
  qkbias_kernel<<<8192, 256, 0, stream>>>(qkvt, kde, biasD);
  attn_kernel<<<1024, 512, 0, stream>>>(qkvt, vt, biasD, vde, Ob);
  gemm_nt<1><<<dim3(8, 64), 256, 0, stream>>>(Ob, Wb_out, b_out, 1024, out, nullptr, 1024);
}

// Round 3
// 309.221 us; speedup vs baseline: 1.4329x; 1.4329x over previous
//
#include <hip/hip_runtime.h>
#include <hip/hip_bf16.h>
#include <cstdint>

// DistanceAwareSelfAttention: SLEN=1024, BSZ=8, H=16, D=64, EMB=1024, CLIP=10
// Pipeline: f2b converts -> GEMM1 (in_proj, scatter to (3,b,h,s,d)) -> vtrans
//           -> qk band-bias table -> flash attention (+band corrections) -> GEMM2 (out_proj)
// R3: attn rewritten — cooperative double-buffered LDS staging of K/V tiles
//     (global_load_lds, XOR-swizzled via pre-swizzled global source), one
//     vmcnt(0)+barrier per tile, XCD-chunked block swizzle, setprio on MFMAs.

typedef __attribute__((ext_vector_type(8))) __bf16 bf16x8;
typedef __attribute__((ext_vector_type(4))) __bf16 bf16x4;
typedef __attribute__((ext_vector_type(4))) float f32x4;

__device__ __forceinline__ void gload_lds16(const void* g, void* l) {
  __builtin_amdgcn_global_load_lds(
      (const __attribute__((address_space(1))) void*)g,
      (__attribute__((address_space(3))) void*)l, 16, 0, 0);
}

__global__ __launch_bounds__(256) void f2b_kernel(const float* __restrict__ src,
                                                  __bf16* __restrict__ dst, int n) {
  int i = (blockIdx.x * 256 + threadIdx.x) * 8;
  if (i >= n) return;
  float4 a = *(const float4*)(src + i);
  float4 b = *(const float4*)(src + i + 4);
  bf16x8 o;
  o[0] = (__bf16)a.x; o[1] = (__bf16)a.y; o[2] = (__bf16)a.z; o[3] = (__bf16)a.w;
  o[4] = (__bf16)b.x; o[5] = (__bf16)b.y; o[6] = (__bf16)b.z; o[7] = (__bf16)b.w;
  *(bf16x8*)(dst + i) = o;
}

// C[m][n] = sum_k A[m][k]*B[n][k] + bias[n].  128x128 tile, BK=64, 4 waves.
// EPI 0: scatter bf16 to qkvt (3,b,h,s,d), scale q by 0.125.  EPI 1: fp32 out.
template <int EPI>
__global__ __launch_bounds__(256) void gemm_nt(
    const __bf16* __restrict__ A, const __bf16* __restrict__ B,
    const float* __restrict__ bias, int K,
    float* __restrict__ outF, __bf16* __restrict__ outT, int N) {
  __shared__ __align__(16) __bf16 sA[128 * 64];
  __shared__ __align__(16) __bf16 sB[128 * 64];
  const int tid = threadIdx.x;
  const int wave = tid >> 6, lane = tid & 63;
  const int lg = lane >> 4, lr = lane & 15;
  const int wr = wave >> 1, wc = wave & 1;
  const int m0 = blockIdx.y * 128;
  const int n0 = blockIdx.x * 128;

  f32x4 acc[4][4] = {};

  for (int kt = 0; kt < K; kt += 64) {
#pragma unroll
    for (int it = 0; it < 4; ++it) {
      int c = it * 256 + tid;
      int r = c >> 3, c8 = (c & 7) * 8;
      gload_lds16(A + (size_t)(m0 + r) * K + kt + c8,
                  (void*)&sA[(it * 256 + wave * 64) * 8]);
      gload_lds16(B + (size_t)(n0 + r) * K + kt + c8,
                  (void*)&sB[(it * 256 + wave * 64) * 8]);
    }
    __syncthreads();
#pragma unroll
    for (int kk = 0; kk < 2; ++kk) {
      bf16x8 af[4], bfr[4];
#pragma unroll
      for (int i = 0; i < 4; ++i)
        af[i] = *(const bf16x8*)&sA[(wr * 64 + i * 16 + lr) * 64 + kk * 32 + lg * 8];
#pragma unroll
      for (int j = 0; j < 4; ++j)
        bfr[j] = *(const bf16x8*)&sB[(wc * 64 + j * 16 + lr) * 64 + kk * 32 + lg * 8];
#pragma unroll
      for (int i = 0; i < 4; ++i)
#pragma unroll
        for (int j = 0; j < 4; ++j)
          acc[i][j] = __builtin_amdgcn_mfma_f32_16x16x32_bf16(af[i], bfr[j], acc[i][j], 0, 0, 0);
    }
    __syncthreads();
  }

#pragma unroll
  for (int i = 0; i < 4; ++i) {
    const int gm0 = m0 + wr * 64 + i * 16 + lg * 4;
#pragma unroll
    for (int j = 0; j < 4; ++j) {
      const int gn = n0 + wc * 64 + j * 16 + lr;
      const float bv = bias[gn];
#pragma unroll
      for (int rg = 0; rg < 4; ++rg) {
        const int gm = gm0 + rg;
        float v = acc[i][j][rg] + bv;
        if constexpr (EPI == 0) {
          int t = gn >> 10, h = (gn >> 6) & 15, d = gn & 63;
          int s = gm >> 3, b = gm & 7;
          if (t == 0) v *= 0.125f;  // q * d^-0.5
          outT[(((size_t)((t * 8 + b) * 16 + h) * 1024 + s) << 6) + d] = (__bf16)v;
        } else {
          outF[(size_t)gm * N + gn] = v;
        }
      }
    }
  }
}

// v (bh,s,d) -> vt (bh,d,s), 64x64 tiles
__global__ __launch_bounds__(256) void vtrans_kernel(const __bf16* __restrict__ v,
                                                     __bf16* __restrict__ vt) {
  __shared__ __bf16 tile[64][66];
  const int tid = threadIdx.x;
  const int bh = blockIdx.x >> 4;
  const int s0 = (blockIdx.x & 15) * 64;
  const __bf16* src = v + ((size_t)bh * 1024 + s0) * 64;
#pragma unroll
  for (int it = 0; it < 4; ++it) {
    int idx = it * 256 + tid;
    int r = idx >> 4, c4 = (idx & 15) * 4;
    bf16x4 x = *(const bf16x4*)&src[r * 64 + c4];
    tile[r][c4 + 0] = x[0]; tile[r][c4 + 1] = x[1];
    tile[r][c4 + 2] = x[2]; tile[r][c4 + 3] = x[3];
  }
  __syncthreads();
  __bf16* dst = vt + (size_t)bh * 65536;
#pragma unroll
  for (int it = 0; it < 4; ++it) {
    int idx = it * 256 + tid;
    int dr = idx >> 4, s4 = (idx & 15) * 4;
    bf16x4 y;
    y[0] = tile[s4 + 0][dr]; y[1] = tile[s4 + 1][dr];
    y[2] = tile[s4 + 2][dr]; y[3] = tile[s4 + 3][dr];
    *(bf16x4*)&dst[(size_t)dr * 1024 + s0 + s4] = y;
  }
}

// biasD[row][c] = q[row]·(kde[c]-kde[10]) for c<10, else 0.  row = bh*1024+s.
__global__ __launch_bounds__(256) void qkbias_kernel(const __bf16* __restrict__ q,
                                                     const float* __restrict__ kde,
                                                     float* __restrict__ biasD) {
  const int row = blockIdx.x * 16 + (threadIdx.x >> 4);
  const int c = threadIdx.x & 15;
  float acc = 0.f;
  if (c < 10) {
    const __bf16* qr = q + (size_t)row * 64;
#pragma unroll
    for (int d = 0; d < 64; ++d)
      acc += (float)qr[d] * (kde[c * 64 + d] - kde[640 + d]);
  }
  biasD[(size_t)row * 16 + c] = acc;
}

// Flash attention w/ distance band.  8 waves, 16 q-rows/wave (Q-tile 128), KV tiles of 64.
// K/V tiles staged once per block into double-buffered LDS; 16B-chunk XOR swizzle
// (chunk ^= row&7) applied on the GLOBAL source address (gload_lds dest is linear,
// rule #21) and on the LDS fragment read.
__global__ __launch_bounds__(512) void attn_kernel(
    const __bf16* __restrict__ qkv, const __bf16* __restrict__ vt,
    const float* __restrict__ biasD, const float* __restrict__ vde,
    __bf16* __restrict__ O) {
  __shared__ __align__(16) __bf16 sK[2][4096];   // [64 t][64 k], swizzled
  __shared__ __align__(16) __bf16 sV[2][4096];   // [64 d][64 t], swizzled
  __shared__ float band[8][16][20];              // band logits, slot = (t-s)+9
  __shared__ __align__(16) __bf16 pbuf[8][16][72];  // per-wave P transpose buffer
  const int tid = threadIdx.x, wave = tid >> 6, lane = tid & 63;
  const int lg = lane >> 4, lr = lane & 15;
  // XCD-chunked bijective swizzle: 1024 blocks -> 8 chunks of 128; all 8
  // stile-blocks of a bh land on one XCD (K/V L2 reuse).
  const int lid = (blockIdx.x & 7) * 128 + (blockIdx.x >> 3);
  const int bh = lid >> 3;
  const int stile = lid & 7;
  const int sb = stile * 128 + wave * 16;
  const int b = bh >> 4, h = bh & 15;
  const __bf16* qp = qkv + (size_t)bh * 65536;
  const __bf16* kp = qkv + (size_t)(128 + bh) * 65536;
  const __bf16* vtp = vt + (size_t)bh * 65536;

  // staging geometry: 512 threads cover one 64x64 bf16 tile (8KB) per tile-op;
  // row = tid>>3 (0..63), 16B chunk = tid&7, source chunk XOR'd by row&7.
  const int srow = tid >> 3;
  const int sc8 = ((tid & 7) ^ (srow & 7)) * 8;  // element offset of source chunk

#define STAGE(BUF, T0)                                                         \
  {                                                                            \
    gload_lds16(kp + (size_t)((T0) + srow) * 64 + sc8, &sK[BUF][wave * 512]);  \
    gload_lds16(vtp + (size_t)srow * 1024 + (T0) + sc8, &sV[BUF][wave * 512]); \
  }

  {
    float* bf = &band[0][0][0];
    for (int i = tid; i < 8 * 16 * 20; i += 512) bf[i] = -1e30f;
  }

  bf16x8 aq[2];
#pragma unroll
  for (int kk = 0; kk < 2; ++kk)
    aq[kk] = *(const bf16x8*)&qp[(size_t)(sb + lr) * 64 + kk * 32 + lg * 8];

  f32x4 o_acc[4] = {};
  float mrow[4], lrow[4];
#pragma unroll
  for (int r = 0; r < 4; ++r) { mrow[r] = -1e30f; lrow[r] = 0.f; }

  // prologue: stage tile 0
  STAGE(0, 0)
  asm volatile("s_waitcnt vmcnt(0)" ::: "memory");
  __syncthreads();

  int buf = 0;
  for (int kt = 0; kt < 16; ++kt) {
    const int t0 = kt * 64;
    if (kt < 15) STAGE(buf ^ 1, t0 + 64)
    const __bf16* kb = sK[buf];
    const __bf16* vb = sV[buf];
    // ---- QK^T from LDS (swizzled reads) ----
    f32x4 sf[4];
    __builtin_amdgcn_s_setprio(1);
#pragma unroll
    for (int tj = 0; tj < 4; ++tj) {
      const int t = tj * 16 + lr;
      bf16x8 bk0 = *(const bf16x8*)&kb[t * 64 + ((lg ^ (t & 7)) * 8)];
      bf16x8 bk1 = *(const bf16x8*)&kb[t * 64 + (((4 + lg) ^ (t & 7)) * 8)];
      f32x4 z = {};
      z = __builtin_amdgcn_mfma_f32_16x16x32_bf16(aq[0], bk0, z, 0, 0, 0);
      z = __builtin_amdgcn_mfma_f32_16x16x32_bf16(aq[1], bk1, z, 0, 0, 0);
      sf[tj] = z;
    }
    __builtin_amdgcn_s_setprio(0);
    // ---- distance-band bias (softmax-invariant shift applied) ----
    const bool inband = (t0 <= sb + 24) && (t0 + 63 >= sb - 9);
    if (inband) {
#pragma unroll
      for (int tj = 0; tj < 4; ++tj) {
        const int t = t0 + tj * 16 + lr;
#pragma unroll
        for (int rg = 0; rg < 4; ++rg) {
          const int s = sb + lg * 4 + rg;
          const int dd = t - s;
          const int ad = dd < 0 ? -dd : dd;
          const int c = ad < 15 ? ad : 15;
          const float val = sf[tj][rg] + biasD[((size_t)bh * 1024 + s) * 16 + c];
          sf[tj][rg] = val;
          if (ad <= 9) band[wave][lg * 4 + rg][dd + 9] = val;
        }
      }
    }
    // ---- online softmax ----
    float vmax[4];
#pragma unroll
    for (int rg = 0; rg < 4; ++rg)
      vmax[rg] = fmaxf(fmaxf(sf[0][rg], sf[1][rg]), fmaxf(sf[2][rg], sf[3][rg]));
#pragma unroll
    for (int off = 1; off < 16; off <<= 1)
#pragma unroll
      for (int rg = 0; rg < 4; ++rg)
        vmax[rg] = fmaxf(vmax[rg], __shfl_xor(vmax[rg], off, 64));
    float scl[4];
#pragma unroll
    for (int rg = 0; rg < 4; ++rg) {
      float mn = fmaxf(mrow[rg], vmax[rg]);
      scl[rg] = __expf(mrow[rg] - mn);
      mrow[rg] = mn;
    }
    float rsum[4] = {0.f, 0.f, 0.f, 0.f};
#pragma unroll
    for (int tj = 0; tj < 4; ++tj)
#pragma unroll
      for (int rg = 0; rg < 4; ++rg) {
        float p = __expf(sf[tj][rg] - mrow[rg]);
        sf[tj][rg] = p;
        rsum[rg] += p;
      }
#pragma unroll
    for (int off = 1; off < 16; off <<= 1)
#pragma unroll
      for (int rg = 0; rg < 4; ++rg)
        rsum[rg] += __shfl_xor(rsum[rg], off, 64);
#pragma unroll
    for (int rg = 0; rg < 4; ++rg)
      lrow[rg] = lrow[rg] * scl[rg] + rsum[rg];
#pragma unroll
    for (int dj = 0; dj < 4; ++dj)
#pragma unroll
      for (int rg = 0; rg < 4; ++rg)
        o_acc[dj][rg] *= scl[rg];
    // ---- P -> LDS (lane transpose for PV A-operand) ----
#pragma unroll
    for (int tj = 0; tj < 4; ++tj)
#pragma unroll
      for (int rg = 0; rg < 4; ++rg)
        pbuf[wave][lg * 4 + rg][tj * 16 + lr] = (__bf16)sf[tj][rg];
    asm volatile("s_waitcnt lgkmcnt(0)" ::: "memory");
    __builtin_amdgcn_sched_barrier(0);
    // ---- PV from LDS (swizzled V reads) ----
    bf16x8 pa[2];
#pragma unroll
    for (int kk = 0; kk < 2; ++kk)
      pa[kk] = *(const bf16x8*)&pbuf[wave][lr][kk * 32 + lg * 8];
    __builtin_amdgcn_s_setprio(1);
#pragma unroll
    for (int dj = 0; dj < 4; ++dj) {
      const int d = dj * 16 + lr;
      bf16x8 bv0 = *(const bf16x8*)&vb[d * 64 + ((lg ^ (d & 7)) * 8)];
      bf16x8 bv1 = *(const bf16x8*)&vb[d * 64 + (((4 + lg) ^ (d & 7)) * 8)];
      o_acc[dj] = __builtin_amdgcn_mfma_f32_16x16x32_bf16(pa[0], bv0, o_acc[dj], 0, 0, 0);
      o_acc[dj] = __builtin_amdgcn_mfma_f32_16x16x32_bf16(pa[1], bv1, o_acc[dj], 0, 0, 0);
    }
    __builtin_amdgcn_s_setprio(0);
    // next-tile stage must be complete before all waves proceed
    asm volatile("s_waitcnt vmcnt(0)" ::: "memory");
    __syncthreads();
    buf ^= 1;
  }
#undef STAGE

  // ---- epilogue: normalize + v_dist band correction, write (s,b,h*d) bf16 ----
#pragma unroll
  for (int rg = 0; rg < 4; ++rg) {
    const int rl = lg * 4 + rg;
    const int s = sb + rl;
    const float inv = 1.f / lrow[rg];
    float psum[10];
    psum[0] = __expf(band[wave][rl][9] - mrow[rg]);
#pragma unroll
    for (int c = 1; c < 10; ++c)
      psum[c] = __expf(band[wave][rl][9 - c] - mrow[rg]) +
                __expf(band[wave][rl][9 + c] - mrow[rg]);
#pragma unroll
    for (int dj = 0; dj < 4; ++dj) {
      const int d = dj * 16 + lr;
      float acc2 = 0.f;
#pragma unroll
      for (int c = 0; c < 10; ++c)
        acc2 += psum[c] * (vde[c * 64 + d] - vde[640 + d]);
      float val = (o_acc[dj][rg] + acc2) * inv + vde[640 + d];
      O[((size_t)(s * 8 + b)) * 1024 + h * 64 + d] = (__bf16)val;
    }
  }
}

extern "C" void kernel_launch(void* const* d_in, const int* in_sizes, int n_in,
                              void* d_out, int out_size, void* d_ws, size_t ws_size,
                              hipStream_t stream) {
  (void)in_sizes; (void)n_in; (void)out_size; (void)ws_size;
  const float* inputs = (const float*)d_in[0];
  const float* W_in   = (const float*)d_in[1];
  const float* b_in   = (const float*)d_in[2];
  const float* kde    = (const float*)d_in[3];
  const float* vde    = (const float*)d_in[4];
  const float* W_out  = (const float*)d_in[5];
  const float* b_out  = (const float*)d_in[6];
  float* out = (float*)d_out;

  char* ws = (char*)d_ws;
  __bf16* qkvt  = (__bf16*)(ws);              // (3,8,16,1024,64) bf16: 50331648 B
  __bf16* vt    = (__bf16*)(ws + 50331648);   // (128,64,1024)  bf16: 16777216 B
  float*  biasD = (float*) (ws + 67108864);   // (131072,16)    f32:   8388608 B
  __bf16* Xb    = (__bf16*)(ws + 75497472);   // (8192,1024)    bf16: 16777216 B
  __bf16* Ob    = (__bf16*)(ws + 75497472);   // reuse Xb region after GEMM1
  __bf16* Wb_in = (__bf16*)(ws + 92274688);   // (3072,1024)    bf16:  6291456 B
  __bf16* Wb_out= (__bf16*)(ws + 98566144);   // (1024,1024)    bf16:  2097152 B

  f2b_kernel<<<4096, 256, 0, stream>>>(inputs, Xb, 8388608);
  f2b_kernel<<<1536, 256, 0, stream>>>(W_in, Wb_in, 3145728);
  f2b_kernel<<<512, 256, 0, stream>>>(W_out, Wb_out, 1048576);

  gemm_nt<0><<<dim3(24, 64), 256, 0, stream>>>(Xb, Wb_in, b_in, 1024, nullptr, qkvt, 3072);
  vtrans_kernel<<<2048, 256, 0, stream>>>(qkvt + (size_t)2 * 128 * 65536, vt);
  qkbias_kernel<<<8192, 256, 0, stream>>>(qkvt, kde, biasD);
  attn_kernel<<<1024, 512, 0, stream>>>(qkvt, vt, biasD, vde, Ob);
  gemm_nt<1><<<dim3(8, 64), 256, 0, stream>>>(Ob, Wb_out, b_out, 1024, out, nullptr, 1024);
}

// Round 5
// 267.259 us; speedup vs baseline: 1.6579x; 1.1570x over previous
//
#include <hip/hip_runtime.h>
#include <hip/hip_bf16.h>
#include <cstdint>

// DistanceAwareSelfAttention: SLEN=1024, BSZ=8, H=16, D=64, EMB=1024, CLIP=10
// Pipeline: f2b converts -> GEMM1 (in_proj, scatter to (3,b,h,s,d)) -> vtrans
//           -> qk band-bias table -> flash attention (+band corrections) -> GEMM2 (out_proj)
// R5: R4 structure (swapped QK^T -> per-lane softmax; PV via 16x16x16 whose B-frag
//     layout equals S^T's C-layout -> no P redistribution) but PV MFMA through the
//     BUILTIN (hazard-managed) instead of raw inline asm, which skipped the
//     backend's mandatory MFMA wait-state insertion (R4 NaN root cause).

typedef __attribute__((ext_vector_type(8))) __bf16 bf16x8;
typedef __attribute__((ext_vector_type(4))) __bf16 bf16x4;
typedef __attribute__((ext_vector_type(4))) short s16x4;
typedef __attribute__((ext_vector_type(4))) float f32x4;

#if __has_builtin(__builtin_amdgcn_mfma_f32_16x16x16bf16_1k)
#define PV_MFMA(ACC, AV, BV) \
  ACC = __builtin_amdgcn_mfma_f32_16x16x16bf16_1k( \
      __builtin_bit_cast(s16x4, AV), __builtin_bit_cast(s16x4, BV), ACC, 0, 0, 0)
#elif __has_builtin(__builtin_amdgcn_mfma_f32_16x16x16_bf16)
#define PV_MFMA(ACC, AV, BV) \
  ACC = __builtin_amdgcn_mfma_f32_16x16x16_bf16(AV, BV, ACC, 0, 0, 0)
#else
#define PV_MFMA(ACC, AV, BV)                                               \
  asm volatile("s_nop 1\n\tv_mfma_f32_16x16x16_bf16 %0, %1, %2, %0\n\t"    \
               "s_nop 7\n\ts_nop 7"                                        \
               : "+v"(ACC)                                                 \
               : "v"(__builtin_bit_cast(s16x4, AV)),                       \
                 "v"(__builtin_bit_cast(s16x4, BV)))
#endif

__device__ __forceinline__ void gload_lds16(const void* g, void* l) {
  __builtin_amdgcn_global_load_lds(
      (const __attribute__((address_space(1))) void*)g,
      (__attribute__((address_space(3))) void*)l, 16, 0, 0);
}

__global__ __launch_bounds__(256) void f2b_kernel(const float* __restrict__ src,
                                                  __bf16* __restrict__ dst, int n) {
  int i = (blockIdx.x * 256 + threadIdx.x) * 8;
  if (i >= n) return;
  float4 a = *(const float4*)(src + i);
  float4 b = *(const float4*)(src + i + 4);
  bf16x8 o;
  o[0] = (__bf16)a.x; o[1] = (__bf16)a.y; o[2] = (__bf16)a.z; o[3] = (__bf16)a.w;
  o[4] = (__bf16)b.x; o[5] = (__bf16)b.y; o[6] = (__bf16)b.z; o[7] = (__bf16)b.w;
  *(bf16x8*)(dst + i) = o;
}

// C[m][n] = sum_k A[m][k]*B[n][k] + bias[n].  128x128 tile, BK=64, 4 waves.
// EPI 0: scatter bf16 to qkvt (3,b,h,s,d), scale q by 0.125.  EPI 1: fp32 out.
template <int EPI>
__global__ __launch_bounds__(256) void gemm_nt(
    const __bf16* __restrict__ A, const __bf16* __restrict__ B,
    const float* __restrict__ bias, int K,
    float* __restrict__ outF, __bf16* __restrict__ outT, int N) {
  __shared__ __align__(16) __bf16 sA[128 * 64];
  __shared__ __align__(16) __bf16 sB[128 * 64];
  const int tid = threadIdx.x;
  const int wave = tid >> 6, lane = tid & 63;
  const int lg = lane >> 4, lr = lane & 15;
  const int wr = wave >> 1, wc = wave & 1;
  const int m0 = blockIdx.y * 128;
  const int n0 = blockIdx.x * 128;

  f32x4 acc[4][4] = {};

  for (int kt = 0; kt < K; kt += 64) {
#pragma unroll
    for (int it = 0; it < 4; ++it) {
      int c = it * 256 + tid;
      int r = c >> 3, c8 = (c & 7) * 8;
      gload_lds16(A + (size_t)(m0 + r) * K + kt + c8,
                  (void*)&sA[(it * 256 + wave * 64) * 8]);
      gload_lds16(B + (size_t)(n0 + r) * K + kt + c8,
                  (void*)&sB[(it * 256 + wave * 64) * 8]);
    }
    __syncthreads();
#pragma unroll
    for (int kk = 0; kk < 2; ++kk) {
      bf16x8 af[4], bfr[4];
#pragma unroll
      for (int i = 0; i < 4; ++i)
        af[i] = *(const bf16x8*)&sA[(wr * 64 + i * 16 + lr) * 64 + kk * 32 + lg * 8];
#pragma unroll
      for (int j = 0; j < 4; ++j)
        bfr[j] = *(const bf16x8*)&sB[(wc * 64 + j * 16 + lr) * 64 + kk * 32 + lg * 8];
#pragma unroll
      for (int i = 0; i < 4; ++i)
#pragma unroll
        for (int j = 0; j < 4; ++j)
          acc[i][j] = __builtin_amdgcn_mfma_f32_16x16x32_bf16(af[i], bfr[j], acc[i][j], 0, 0, 0);
    }
    __syncthreads();
  }

#pragma unroll
  for (int i = 0; i < 4; ++i) {
    const int gm0 = m0 + wr * 64 + i * 16 + lg * 4;
#pragma unroll
    for (int j = 0; j < 4; ++j) {
      const int gn = n0 + wc * 64 + j * 16 + lr;
      const float bv = bias[gn];
#pragma unroll
      for (int rg = 0; rg < 4; ++rg) {
        const int gm = gm0 + rg;
        float v = acc[i][j][rg] + bv;
        if constexpr (EPI == 0) {
          int t = gn >> 10, h = (gn >> 6) & 15, d = gn & 63;
          int s = gm >> 3, b = gm & 7;
          if (t == 0) v *= 0.125f;  // q * d^-0.5
          outT[(((size_t)((t * 8 + b) * 16 + h) * 1024 + s) << 6) + d] = (__bf16)v;
        } else {
          outF[(size_t)gm * N + gn] = v;
        }
      }
    }
  }
}

// v (bh,s,d) -> vt (bh,d,s), 64x64 tiles
__global__ __launch_bounds__(256) void vtrans_kernel(const __bf16* __restrict__ v,
                                                     __bf16* __restrict__ vt) {
  __shared__ __bf16 tile[64][66];
  const int tid = threadIdx.x;
  const int bh = blockIdx.x >> 4;
  const int s0 = (blockIdx.x & 15) * 64;
  const __bf16* src = v + ((size_t)bh * 1024 + s0) * 64;
#pragma unroll
  for (int it = 0; it < 4; ++it) {
    int idx = it * 256 + tid;
    int r = idx >> 4, c4 = (idx & 15) * 4;
    bf16x4 x = *(const bf16x4*)&src[r * 64 + c4];
    tile[r][c4 + 0] = x[0]; tile[r][c4 + 1] = x[1];
    tile[r][c4 + 2] = x[2]; tile[r][c4 + 3] = x[3];
  }
  __syncthreads();
  __bf16* dst = vt + (size_t)bh * 65536;
#pragma unroll
  for (int it = 0; it < 4; ++it) {
    int idx = it * 256 + tid;
    int dr = idx >> 4, s4 = (idx & 15) * 4;
    bf16x4 y;
    y[0] = tile[s4 + 0][dr]; y[1] = tile[s4 + 1][dr];
    y[2] = tile[s4 + 2][dr]; y[3] = tile[s4 + 3][dr];
    *(bf16x4*)&dst[(size_t)dr * 1024 + s0 + s4] = y;
  }
}

// biasD[row][c] = q[row]·(kde[c]-kde[10]) for c<10, else 0.  row = bh*1024+s.
__global__ __launch_bounds__(256) void qkbias_kernel(const __bf16* __restrict__ q,
                                                     const float* __restrict__ kde,
                                                     float* __restrict__ biasD) {
  const int row = blockIdx.x * 16 + (threadIdx.x >> 4);
  const int c = threadIdx.x & 15;
  float acc = 0.f;
  if (c < 10) {
    const __bf16* qr = q + (size_t)row * 64;
#pragma unroll
    for (int d = 0; d < 64; ++d)
      acc += (float)qr[d] * (kde[c * 64 + d] - kde[640 + d]);
  }
  biasD[(size_t)row * 16 + c] = acc;
}

// Flash attention w/ distance band.  8 waves, 16 q-rows/wave (Q-tile 128), KV tiles of 64.
// Swapped QK^T: sf[tj] = mfma(K-frag, Q-frag) = S^T block; lane owns q = lr.
//   sf[tj][rg] = S[t = t0+16*tj+4*lg+rg][q = sb+lr].
// PV: O^T accumulate via mfma_f32_16x16x16_bf16 — S^T C-layout == its B-frag layout.
//   o_acc[dj][rg] = O^T[d = 16*dj+4*lg+rg][q = sb+lr].
__global__ __launch_bounds__(512) void attn_kernel(
    const __bf16* __restrict__ qkv, const __bf16* __restrict__ vt,
    const float* __restrict__ biasD, const float* __restrict__ vde,
    __bf16* __restrict__ O) {
  __shared__ __align__(16) __bf16 sK[2][4096];   // [64 t][64 k], 16B-chunk XOR swizzled
  __shared__ __align__(16) __bf16 sV[2][4096];   // [64 d][64 t], 16B-chunk XOR swizzled
  __shared__ float band[8][16][20];              // band logits, slot = (t-s)+9, row = lr
  const int tid = threadIdx.x, wave = tid >> 6, lane = tid & 63;
  const int lg = lane >> 4, lr = lane & 15;
  // XCD-chunked bijective swizzle: all 8 stile-blocks of a bh land on one XCD.
  const int lid = (blockIdx.x & 7) * 128 + (blockIdx.x >> 3);
  const int bh = lid >> 3;
  const int stile = lid & 7;
  const int sb = stile * 128 + wave * 16;
  const int b = bh >> 4, h = bh & 15;
  const __bf16* qp = qkv + (size_t)bh * 65536;
  const __bf16* kp = qkv + (size_t)(128 + bh) * 65536;
  const __bf16* vtp = vt + (size_t)bh * 65536;

  // staging: 512 threads cover one 64x64 bf16 tile; row=tid>>3, chunk=tid&7,
  // source chunk XOR'd by row&7 (gload_lds dest linear, rule #21).
  const int srow = tid >> 3;
  const int sc8 = ((tid & 7) ^ (srow & 7)) * 8;

#define STAGE(BUF, T0)                                                         \
  {                                                                            \
    gload_lds16(kp + (size_t)((T0) + srow) * 64 + sc8, &sK[BUF][wave * 512]);  \
    gload_lds16(vtp + (size_t)srow * 1024 + (T0) + sc8, &sV[BUF][wave * 512]); \
  }

  {
    float* bf = &band[0][0][0];
    for (int i = tid; i < 8 * 16 * 20; i += 512) bf[i] = -1e30f;
  }

  bf16x8 aq[2];
#pragma unroll
  for (int kk = 0; kk < 2; ++kk)
    aq[kk] = *(const bf16x8*)&qp[(size_t)(sb + lr) * 64 + kk * 32 + lg * 8];

  f32x4 o_acc[4] = {};
  float m = -1e30f, l = 0.f;
  const int s = sb + lr;  // this lane's q row (replicated across lg groups)

  // prologue: stage tile 0
  STAGE(0, 0)
  asm volatile("s_waitcnt vmcnt(0)" ::: "memory");
  __syncthreads();

  int buf = 0;
  for (int kt = 0; kt < 16; ++kt) {
    const int t0 = kt * 64;
    if (kt < 15) STAGE(buf ^ 1, t0 + 64)
    const __bf16* kb = sK[buf];
    const __bf16* vb = sV[buf];
    // ---- QK^T swapped: sf[tj] = S^T (rows t, cols q) ----
    f32x4 sf[4];
    __builtin_amdgcn_s_setprio(1);
#pragma unroll
    for (int tj = 0; tj < 4; ++tj) {
      const int t = tj * 16 + lr;
      bf16x8 bk0 = *(const bf16x8*)&kb[t * 64 + ((lg ^ (t & 7)) * 8)];
      bf16x8 bk1 = *(const bf16x8*)&kb[t * 64 + (((4 + lg) ^ (t & 7)) * 8)];
      f32x4 z = {};
      z = __builtin_amdgcn_mfma_f32_16x16x32_bf16(bk0, aq[0], z, 0, 0, 0);
      z = __builtin_amdgcn_mfma_f32_16x16x32_bf16(bk1, aq[1], z, 0, 0, 0);
      sf[tj] = z;
    }
    __builtin_amdgcn_s_setprio(0);
    // ---- distance-band bias (softmax-invariant shift applied) ----
    const bool inband = (t0 <= sb + 24) && (t0 + 63 >= sb - 9);
    if (inband) {
      const float* bDrow = biasD + ((size_t)bh * 1024 + s) * 16;
#pragma unroll
      for (int tj = 0; tj < 4; ++tj) {
#pragma unroll
        for (int rg = 0; rg < 4; ++rg) {
          const int t = t0 + tj * 16 + lg * 4 + rg;
          const int dd = t - s;
          const int ad = dd < 0 ? -dd : dd;
          const int c = ad < 15 ? ad : 15;
          const float val = sf[tj][rg] + bDrow[c];
          sf[tj][rg] = val;
          if (ad <= 9) band[wave][lr][dd + 9] = val;
        }
      }
    }
    // ---- online softmax: in-register max over 16 + 2 cross-lane ops ----
    float vm[4];
#pragma unroll
    for (int tj = 0; tj < 4; ++tj)
      vm[tj] = fmaxf(fmaxf(sf[tj][0], sf[tj][1]), fmaxf(sf[tj][2], sf[tj][3]));
    float vmax = fmaxf(fmaxf(vm[0], vm[1]), fmaxf(vm[2], vm[3]));
    vmax = fmaxf(vmax, __shfl_xor(vmax, 16, 64));
    vmax = fmaxf(vmax, __shfl_xor(vmax, 32, 64));
    // defer-max (T13): rescale only when max grows beyond THR=8
    if (__any(vmax > m + 8.f)) {
      const float mn = fmaxf(m, vmax);
      const float scl = __expf(m - mn);
      m = mn;
      l *= scl;
#pragma unroll
      for (int dj = 0; dj < 4; ++dj)
#pragma unroll
        for (int rg = 0; rg < 4; ++rg)
          o_acc[dj][rg] *= scl;
    }
    float rs[4];
#pragma unroll
    for (int tj = 0; tj < 4; ++tj) {
      float p0 = __expf(sf[tj][0] - m), p1 = __expf(sf[tj][1] - m);
      float p2 = __expf(sf[tj][2] - m), p3 = __expf(sf[tj][3] - m);
      sf[tj][0] = p0; sf[tj][1] = p1; sf[tj][2] = p2; sf[tj][3] = p3;
      rs[tj] = (p0 + p1) + (p2 + p3);
    }
    float rsum = (rs[0] + rs[1]) + (rs[2] + rs[3]);
    rsum += __shfl_xor(rsum, 16, 64);
    rsum += __shfl_xor(rsum, 32, 64);
    l += rsum;
    // ---- P -> bf16 B-frags in-register (C-layout == 16x16x16 B-frag layout) ----
    bf16x4 pbv[4];
#pragma unroll
    for (int tj = 0; tj < 4; ++tj) {
      pbv[tj][0] = (__bf16)sf[tj][0]; pbv[tj][1] = (__bf16)sf[tj][1];
      pbv[tj][2] = (__bf16)sf[tj][2]; pbv[tj][3] = (__bf16)sf[tj][3];
    }
    // ---- PV: O^T += V^T-frag · P-frag  (16x mfma 16x16x16) ----
    __builtin_amdgcn_s_setprio(1);
#pragma unroll
    for (int tj = 0; tj < 4; ++tj) {
#pragma unroll
      for (int dj = 0; dj < 4; ++dj) {
        const int d = dj * 16 + lr;
        const int ch = (2 * tj + (lg >> 1)) ^ (d & 7);
        const bf16x4 av = *(const bf16x4*)&vb[d * 64 + ch * 8 + (lg & 1) * 4];
        PV_MFMA(o_acc[dj], av, pbv[tj]);
      }
    }
    __builtin_amdgcn_s_setprio(0);
    // next-tile stage must be complete before all waves proceed
    asm volatile("s_waitcnt vmcnt(0)" ::: "memory");
    __syncthreads();
    buf ^= 1;
  }
#undef STAGE

  // ---- epilogue: normalize + v_dist band correction, write (s,b,h*d) bf16 ----
  const float inv = 1.f / l;
  float psum[10];
  psum[0] = __expf(band[wave][lr][9] - m);
#pragma unroll
  for (int c = 1; c < 10; ++c)
    psum[c] = __expf(band[wave][lr][9 - c] - m) +
              __expf(band[wave][lr][9 + c] - m);
#pragma unroll
  for (int dj = 0; dj < 4; ++dj) {
    bf16x4 ov;
#pragma unroll
    for (int rg = 0; rg < 4; ++rg) {
      const int d = dj * 16 + lg * 4 + rg;
      float acc2 = 0.f;
#pragma unroll
      for (int c = 0; c < 10; ++c)
        acc2 += psum[c] * (vde[c * 64 + d] - vde[640 + d]);
      ov[rg] = (__bf16)((o_acc[dj][rg] + acc2) * inv + vde[640 + d]);
    }
    *(bf16x4*)&O[((size_t)(s * 8 + b)) * 1024 + h * 64 + dj * 16 + lg * 4] = ov;
  }
}

extern "C" void kernel_launch(void* const* d_in, const int* in_sizes, int n_in,
                              void* d_out, int out_size, void* d_ws, size_t ws_size,
                              hipStream_t stream) {
  (void)in_sizes; (void)n_in; (void)out_size; (void)ws_size;
  const float* inputs = (const float*)d_in[0];
  const float* W_in   = (const float*)d_in[1];
  const float* b_in   = (const float*)d_in[2];
  const float* kde    = (const float*)d_in[3];
  const float* vde    = (const float*)d_in[4];
  const float* W_out  = (const float*)d_in[5];
  const float* b_out  = (const float*)d_in[6];
  float* out = (float*)d_out;

  char* ws = (char*)d_ws;
  __bf16* qkvt  = (__bf16*)(ws);              // (3,8,16,1024,64) bf16: 50331648 B
  __bf16* vt    = (__bf16*)(ws + 50331648);   // (128,64,1024)  bf16: 16777216 B
  float*  biasD = (float*) (ws + 67108864);   // (131072,16)    f32:   8388608 B
  __bf16* Xb    = (__bf16*)(ws + 75497472);   // (8192,1024)    bf16: 16777216 B
  __bf16* Ob    = (__bf16*)(ws + 75497472);   // reuse Xb region after GEMM1
  __bf16* Wb_in = (__bf16*)(ws + 92274688);   // (3072,1024)    bf16:  6291456 B
  __bf16* Wb_out= (__bf16*)(ws + 98566144);   // (1024,1024)    bf16:  2097152 B

  f2b_kernel<<<4096, 256, 0, stream>>>(inputs, Xb, 8388608);
  f2b_kernel<<<1536, 256, 0, stream>>>(W_in, Wb_in, 3145728);
  f2b_kernel<<<512, 256, 0, stream>>>(W_out, Wb_out, 1048576);

  gemm_nt<0><<<dim3(24, 64), 256, 0, stream>>>(Xb, Wb_in, b_in, 1024, nullptr, qkvt, 3072);
  vtrans_kernel<<<2048, 256, 0, stream>>>(qkvt + (size_t)2 * 128 * 65536, vt);
  qkbias_kernel<<<8192, 256, 0, stream>>>(qkvt, kde, biasD);
  attn_kernel<<<1024, 512, 0, stream>>>(qkvt, vt, biasD, vde, Ob);
  gemm_nt<1><<<dim3(8, 64), 256, 0, stream>>>(Ob, Wb_out, b_out, 1024, out, nullptr, 1024);
}

// Round 7
// 264.552 us; speedup vs baseline: 1.6748x; 1.0102x over previous
//
#include <hip/hip_runtime.h>
#include <hip/hip_bf16.h>
#include <cstdint>

// DistanceAwareSelfAttention: SLEN=1024, BSZ=8, H=16, D=64, EMB=1024, CLIP=10
// Pipeline: f2b converts -> GEMM1 (in_proj, scatter to (3,b,h,s,d)) -> vtrans
//           -> qk band-bias table -> flash attention (+band corrections) -> GEMM2 (out_proj)
// R7: R6 with the compile fix — __exp2f does not exist in this ROCm; use
//     __builtin_amdgcn_exp2f (raw v_exp_f32) with exp2f fallback.

typedef __attribute__((ext_vector_type(8))) __bf16 bf16x8;
typedef __attribute__((ext_vector_type(4))) __bf16 bf16x4;
typedef __attribute__((ext_vector_type(4))) short s16x4;
typedef __attribute__((ext_vector_type(4))) float f32x4;

#if __has_builtin(__builtin_amdgcn_exp2f)
#define EXP2F(x) __builtin_amdgcn_exp2f(x)
#else
#define EXP2F(x) exp2f(x)
#endif

#if __has_builtin(__builtin_amdgcn_mfma_f32_16x16x16bf16_1k)
#define PV_MFMA(ACC, AV, BV) \
  ACC = __builtin_amdgcn_mfma_f32_16x16x16bf16_1k( \
      __builtin_bit_cast(s16x4, AV), __builtin_bit_cast(s16x4, BV), ACC, 0, 0, 0)
#elif __has_builtin(__builtin_amdgcn_mfma_f32_16x16x16_bf16)
#define PV_MFMA(ACC, AV, BV) \
  ACC = __builtin_amdgcn_mfma_f32_16x16x16_bf16(AV, BV, ACC, 0, 0, 0)
#else
#define PV_MFMA(ACC, AV, BV)                                               \
  asm volatile("s_nop 1\n\tv_mfma_f32_16x16x16_bf16 %0, %1, %2, %0\n\t"    \
               "s_nop 7\n\ts_nop 7"                                        \
               : "+v"(ACC)                                                 \
               : "v"(__builtin_bit_cast(s16x4, AV)),                       \
                 "v"(__builtin_bit_cast(s16x4, BV)))
#endif

__device__ __forceinline__ void gload_lds16(const void* g, void* l) {
  __builtin_amdgcn_global_load_lds(
      (const __attribute__((address_space(1))) void*)g,
      (__attribute__((address_space(3))) void*)l, 16, 0, 0);
}

__global__ __launch_bounds__(256) void f2b_kernel(const float* __restrict__ src,
                                                  __bf16* __restrict__ dst, int n) {
  int i = (blockIdx.x * 256 + threadIdx.x) * 8;
  if (i >= n) return;
  float4 a = *(const float4*)(src + i);
  float4 b = *(const float4*)(src + i + 4);
  bf16x8 o;
  o[0] = (__bf16)a.x; o[1] = (__bf16)a.y; o[2] = (__bf16)a.z; o[3] = (__bf16)a.w;
  o[4] = (__bf16)b.x; o[5] = (__bf16)b.y; o[6] = (__bf16)b.z; o[7] = (__bf16)b.w;
  *(bf16x8*)(dst + i) = o;
}

// C[m][n] = sum_k A[m][k]*B[n][k] + bias[n].  128x128 tile, BK=64, 4 waves.
// EPI 0: scatter bf16 to qkvt (3,b,h,s,d), scale q by 0.125*log2e (exp2-domain
//        softmax downstream).  EPI 1: fp32 out.
template <int EPI>
__global__ __launch_bounds__(256) void gemm_nt(
    const __bf16* __restrict__ A, const __bf16* __restrict__ B,
    const float* __restrict__ bias, int K,
    float* __restrict__ outF, __bf16* __restrict__ outT, int N) {
  __shared__ __align__(16) __bf16 sA[128 * 64];
  __shared__ __align__(16) __bf16 sB[128 * 64];
  const int tid = threadIdx.x;
  const int wave = tid >> 6, lane = tid & 63;
  const int lg = lane >> 4, lr = lane & 15;
  const int wr = wave >> 1, wc = wave & 1;
  const int m0 = blockIdx.y * 128;
  const int n0 = blockIdx.x * 128;

  f32x4 acc[4][4] = {};

  for (int kt = 0; kt < K; kt += 64) {
#pragma unroll
    for (int it = 0; it < 4; ++it) {
      int c = it * 256 + tid;
      int r = c >> 3, c8 = (c & 7) * 8;
      gload_lds16(A + (size_t)(m0 + r) * K + kt + c8,
                  (void*)&sA[(it * 256 + wave * 64) * 8]);
      gload_lds16(B + (size_t)(n0 + r) * K + kt + c8,
                  (void*)&sB[(it * 256 + wave * 64) * 8]);
    }
    __syncthreads();
#pragma unroll
    for (int kk = 0; kk < 2; ++kk) {
      bf16x8 af[4], bfr[4];
#pragma unroll
      for (int i = 0; i < 4; ++i)
        af[i] = *(const bf16x8*)&sA[(wr * 64 + i * 16 + lr) * 64 + kk * 32 + lg * 8];
#pragma unroll
      for (int j = 0; j < 4; ++j)
        bfr[j] = *(const bf16x8*)&sB[(wc * 64 + j * 16 + lr) * 64 + kk * 32 + lg * 8];
#pragma unroll
      for (int i = 0; i < 4; ++i)
#pragma unroll
        for (int j = 0; j < 4; ++j)
          acc[i][j] = __builtin_amdgcn_mfma_f32_16x16x32_bf16(af[i], bfr[j], acc[i][j], 0, 0, 0);
    }
    __syncthreads();
  }

#pragma unroll
  for (int i = 0; i < 4; ++i) {
    const int gm0 = m0 + wr * 64 + i * 16 + lg * 4;
#pragma unroll
    for (int j = 0; j < 4; ++j) {
      const int gn = n0 + wc * 64 + j * 16 + lr;
      const float bv = bias[gn];
#pragma unroll
      for (int rg = 0; rg < 4; ++rg) {
        const int gm = gm0 + rg;
        float v = acc[i][j][rg] + bv;
        if constexpr (EPI == 0) {
          int t = gn >> 10, h = (gn >> 6) & 15, d = gn & 63;
          int s = gm >> 3, b = gm & 7;
          if (t == 0) v *= 0.18033688011112042f;  // d^-0.5 * log2(e)
          outT[(((size_t)((t * 8 + b) * 16 + h) * 1024 + s) << 6) + d] = (__bf16)v;
        } else {
          outF[(size_t)gm * N + gn] = v;
        }
      }
    }
  }
}

// v (bh,s,d) -> vt (bh,d,s), 64x64 tiles
__global__ __launch_bounds__(256) void vtrans_kernel(const __bf16* __restrict__ v,
                                                     __bf16* __restrict__ vt) {
  __shared__ __bf16 tile[64][66];
  const int tid = threadIdx.x;
  const int bh = blockIdx.x >> 4;
  const int s0 = (blockIdx.x & 15) * 64;
  const __bf16* src = v + ((size_t)bh * 1024 + s0) * 64;
#pragma unroll
  for (int it = 0; it < 4; ++it) {
    int idx = it * 256 + tid;
    int r = idx >> 4, c4 = (idx & 15) * 4;
    bf16x4 x = *(const bf16x4*)&src[r * 64 + c4];
    tile[r][c4 + 0] = x[0]; tile[r][c4 + 1] = x[1];
    tile[r][c4 + 2] = x[2]; tile[r][c4 + 3] = x[3];
  }
  __syncthreads();
  __bf16* dst = vt + (size_t)bh * 65536;
#pragma unroll
  for (int it = 0; it < 4; ++it) {
    int idx = it * 256 + tid;
    int dr = idx >> 4, s4 = (idx & 15) * 4;
    bf16x4 y;
    y[0] = tile[s4 + 0][dr]; y[1] = tile[s4 + 1][dr];
    y[2] = tile[s4 + 2][dr]; y[3] = tile[s4 + 3][dr];
    *(bf16x4*)&dst[(size_t)dr * 1024 + s0 + s4] = y;
  }
}

// biasD[row][c] = q[row]·(kde[c]-kde[10]) for c<10, else 0.  row = bh*1024+s.
// q already carries log2e, so biasD is in the exp2 domain too.
__global__ __launch_bounds__(256) void qkbias_kernel(const __bf16* __restrict__ q,
                                                     const float* __restrict__ kde,
                                                     float* __restrict__ biasD) {
  const int row = blockIdx.x * 16 + (threadIdx.x >> 4);
  const int c = threadIdx.x & 15;
  float acc = 0.f;
  if (c < 10) {
    const bf16x8* qr = (const bf16x8*)(q + (size_t)row * 64);
#pragma unroll
    for (int d8 = 0; d8 < 8; ++d8) {
      bf16x8 qv = qr[d8];
#pragma unroll
      for (int j = 0; j < 8; ++j)
        acc += (float)qv[j] * (kde[c * 64 + d8 * 8 + j] - kde[640 + d8 * 8 + j]);
    }
  }
  biasD[(size_t)row * 16 + c] = acc;
}

// Flash attention w/ distance band.  8 waves, 16 q-rows/wave (Q-tile 128), KV tiles of 64.
// Swapped QK^T: sf[tj] = mfma(K,Q) = S^T; lane owns q = lr; per-lane softmax state.
// PV: O^T accumulate via mfma_16x16x16 (S^T C-layout == its B-frag layout).
// Staging: triple-buffered, stage(t+2) at top, counted vmcnt(2) + raw s_barrier at
// bottom (2-tile latency budget; never drain to 0 mid-loop).
__global__ __launch_bounds__(512) void attn_kernel(
    const __bf16* __restrict__ qkv, const __bf16* __restrict__ vt,
    const float* __restrict__ biasD, const float* __restrict__ vde,
    __bf16* __restrict__ O) {
  __shared__ __align__(16) __bf16 sK[3][4096];   // [64 t][64 k], 16B-chunk XOR swizzled
  __shared__ __align__(16) __bf16 sV[3][4096];   // [64 d][64 t], 16B-chunk XOR swizzled
  __shared__ float band[8][16][20];              // band logits (log2 dom), slot=(t-s)+9
  const int tid = threadIdx.x, wave = tid >> 6, lane = tid & 63;
  const int lg = lane >> 4, lr = lane & 15;
  // XCD-chunked bijective swizzle: all 8 stile-blocks of a bh land on one XCD.
  const int lid = (blockIdx.x & 7) * 128 + (blockIdx.x >> 3);
  const int bh = lid >> 3;
  const int stile = lid & 7;
  const int sb = stile * 128 + wave * 16;
  const int b = bh >> 4, h = bh & 15;
  const __bf16* qp = qkv + (size_t)bh * 65536;
  const __bf16* kp = qkv + (size_t)(128 + bh) * 65536;
  const __bf16* vtp = vt + (size_t)bh * 65536;

  // staging: 512 threads cover one 64x64 bf16 tile; row=tid>>3, chunk=tid&7,
  // source chunk XOR'd by row&7 (gload_lds dest linear, rule #21).
  const int srow = tid >> 3;
  const int sc8 = ((tid & 7) ^ (srow & 7)) * 8;

#define STAGE(BUF, T0)                                                         \
  {                                                                            \
    gload_lds16(kp + (size_t)((T0) + srow) * 64 + sc8, &sK[BUF][wave * 512]);  \
    gload_lds16(vtp + (size_t)srow * 1024 + (T0) + sc8, &sV[BUF][wave * 512]); \
  }

  // prologue: stage tiles 0,1 (2 deep)
  STAGE(0, 0)
  STAGE(1, 64)

  {
    float* bf = &band[0][0][0];
    for (int i = tid; i < 8 * 16 * 20; i += 512) bf[i] = -1e30f;
  }

  bf16x8 aq[2];
#pragma unroll
  for (int kk = 0; kk < 2; ++kk)
    aq[kk] = *(const bf16x8*)&qp[(size_t)(sb + lr) * 64 + kk * 32 + lg * 8];

  f32x4 o_acc[4] = {};
  float m = -1e30f, l = 0.f;
  const int s = sb + lr;  // this lane's q row (replicated across lg groups)

  // wait for stage(0) only (2 ops of stage(1) may remain outstanding)
  asm volatile("s_waitcnt vmcnt(2)" ::: "memory");
  __builtin_amdgcn_s_barrier();

  int bc = 0;  // compute buffer = kt%3
  int bs = 2;  // stage buffer   = (kt+2)%3
  for (int kt = 0; kt < 16; ++kt) {
    const int t0 = kt * 64;
    if (kt < 14) STAGE(bs, t0 + 128)
    const __bf16* kb = sK[bc];
    const __bf16* vb = sV[bc];
    // ---- QK^T swapped: sf[tj] = S^T (rows t, cols q), log2 domain ----
    f32x4 sf[4];
    __builtin_amdgcn_s_setprio(1);
#pragma unroll
    for (int tj = 0; tj < 4; ++tj) {
      const int t = tj * 16 + lr;
      bf16x8 bk0 = *(const bf16x8*)&kb[t * 64 + ((lg ^ (t & 7)) * 8)];
      bf16x8 bk1 = *(const bf16x8*)&kb[t * 64 + (((4 + lg) ^ (t & 7)) * 8)];
      f32x4 z = {};
      z = __builtin_amdgcn_mfma_f32_16x16x32_bf16(bk0, aq[0], z, 0, 0, 0);
      z = __builtin_amdgcn_mfma_f32_16x16x32_bf16(bk1, aq[1], z, 0, 0, 0);
      sf[tj] = z;
    }
    __builtin_amdgcn_s_setprio(0);
    // ---- distance-band bias (softmax-invariant shift applied) ----
    const bool inband = (t0 <= sb + 24) && (t0 + 63 >= sb - 9);
    if (inband) {
      const float* bDrow = biasD + ((size_t)bh * 1024 + s) * 16;
#pragma unroll
      for (int tj = 0; tj < 4; ++tj) {
#pragma unroll
        for (int rg = 0; rg < 4; ++rg) {
          const int t = t0 + tj * 16 + lg * 4 + rg;
          const int dd = t - s;
          const int ad = dd < 0 ? -dd : dd;
          const int c = ad < 15 ? ad : 15;
          const float val = sf[tj][rg] + bDrow[c];
          sf[tj][rg] = val;
          if (ad <= 9) band[wave][lr][dd + 9] = val;
        }
      }
    }
    // ---- online softmax (exp2 domain): in-register max + 2 cross-lane ops ----
    float vm[4];
#pragma unroll
    for (int tj = 0; tj < 4; ++tj)
      vm[tj] = fmaxf(fmaxf(sf[tj][0], sf[tj][1]), fmaxf(sf[tj][2], sf[tj][3]));
    float vmax = fmaxf(fmaxf(vm[0], vm[1]), fmaxf(vm[2], vm[3]));
    vmax = fmaxf(vmax, __shfl_xor(vmax, 16, 64));
    vmax = fmaxf(vmax, __shfl_xor(vmax, 32, 64));
    // defer-max (T13): rescale only when max grows beyond THR=8 (P <= 2^8)
    if (__any(vmax > m + 8.f)) {
      const float mn = fmaxf(m, vmax);
      const float scl = EXP2F(m - mn);
      m = mn;
      l *= scl;
#pragma unroll
      for (int dj = 0; dj < 4; ++dj)
#pragma unroll
        for (int rg = 0; rg < 4; ++rg)
          o_acc[dj][rg] *= scl;
    }
    float rs[4];
#pragma unroll
    for (int tj = 0; tj < 4; ++tj) {
      float p0 = EXP2F(sf[tj][0] - m), p1 = EXP2F(sf[tj][1] - m);
      float p2 = EXP2F(sf[tj][2] - m), p3 = EXP2F(sf[tj][3] - m);
      sf[tj][0] = p0; sf[tj][1] = p1; sf[tj][2] = p2; sf[tj][3] = p3;
      rs[tj] = (p0 + p1) + (p2 + p3);
    }
    float rsum = (rs[0] + rs[1]) + (rs[2] + rs[3]);
    rsum += __shfl_xor(rsum, 16, 64);
    rsum += __shfl_xor(rsum, 32, 64);
    l += rsum;
    // ---- P -> bf16 B-frags in-register (C-layout == 16x16x16 B-frag layout) ----
    bf16x4 pbv[4];
#pragma unroll
    for (int tj = 0; tj < 4; ++tj) {
      pbv[tj][0] = (__bf16)sf[tj][0]; pbv[tj][1] = (__bf16)sf[tj][1];
      pbv[tj][2] = (__bf16)sf[tj][2]; pbv[tj][3] = (__bf16)sf[tj][3];
    }
    // ---- PV: O^T += V^T-frag · P-frag  (16x mfma 16x16x16) ----
    __builtin_amdgcn_s_setprio(1);
#pragma unroll
    for (int tj = 0; tj < 4; ++tj) {
#pragma unroll
      for (int dj = 0; dj < 4; ++dj) {
        const int d = dj * 16 + lr;
        const int ch = (2 * tj + (lg >> 1)) ^ (d & 7);
        const bf16x4 av = *(const bf16x4*)&vb[d * 64 + ch * 8 + (lg & 1) * 4];
        PV_MFMA(o_acc[dj], av, pbv[tj]);
      }
    }
    __builtin_amdgcn_s_setprio(0);
    // counted wait: stage(t+1) must be done; stage(t+2)'s 2 ops stay in flight
    if (kt < 13) {
      asm volatile("s_waitcnt vmcnt(2)" ::: "memory");
    } else if (kt < 15) {
      asm volatile("s_waitcnt vmcnt(0)" ::: "memory");
    }
    if (kt < 15) __builtin_amdgcn_s_barrier();
    bc = (bc == 2) ? 0 : bc + 1;
    bs = (bs == 2) ? 0 : bs + 1;
  }
#undef STAGE

  // ---- epilogue: normalize + v_dist band correction, write (s,b,h*d) bf16 ----
  const float inv = 1.f / l;
  float psum[10];
  psum[0] = EXP2F(band[wave][lr][9] - m);
#pragma unroll
  for (int c = 1; c < 10; ++c)
    psum[c] = EXP2F(band[wave][lr][9 - c] - m) +
              EXP2F(band[wave][lr][9 + c] - m);
#pragma unroll
  for (int dj = 0; dj < 4; ++dj) {
    bf16x4 ov;
#pragma unroll
    for (int rg = 0; rg < 4; ++rg) {
      const int d = dj * 16 + lg * 4 + rg;
      float acc2 = 0.f;
#pragma unroll
      for (int c = 0; c < 10; ++c)
        acc2 += psum[c] * (vde[c * 64 + d] - vde[640 + d]);
      ov[rg] = (__bf16)((o_acc[dj][rg] + acc2) * inv + vde[640 + d]);
    }
    *(bf16x4*)&O[((size_t)(s * 8 + b)) * 1024 + h * 64 + dj * 16 + lg * 4] = ov;
  }
}

extern "C" void kernel_launch(void* const* d_in, const int* in_sizes, int n_in,
                              void* d_out, int out_size, void* d_ws, size_t ws_size,
                              hipStream_t stream) {
  (void)in_sizes; (void)n_in; (void)out_size; (void)ws_size;
  const float* inputs = (const float*)d_in[0];
  const float* W_in   = (const float*)d_in[1];
  const float* b_in   = (const float*)d_in[2];
  const float* kde    = (const float*)d_in[3];
  const float* vde    = (const float*)d_in[4];
  const float* W_out  = (const float*)d_in[5];
  const float* b_out  = (const float*)d_in[6];
  float* out = (float*)d_out;

  char* ws = (char*)d_ws;
  __bf16* qkvt  = (__bf16*)(ws);              // (3,8,16,1024,64) bf16: 50331648 B
  __bf16* vt    = (__bf16*)(ws + 50331648);   // (128,64,1024)  bf16: 16777216 B
  float*  biasD = (float*) (ws + 67108864);   // (131072,16)    f32:   8388608 B
  __bf16* Xb    = (__bf16*)(ws + 75497472);   // (8192,1024)    bf16: 16777216 B
  __bf16* Ob    = (__bf16*)(ws + 75497472);   // reuse Xb region after GEMM1
  __bf16* Wb_in = (__bf16*)(ws + 92274688);   // (3072,1024)    bf16:  6291456 B
  __bf16* Wb_out= (__bf16*)(ws + 98566144);   // (1024,1024)    bf16:  2097152 B

  f2b_kernel<<<4096, 256, 0, stream>>>(inputs, Xb, 8388608);
  f2b_kernel<<<1536, 256, 0, stream>>>(W_in, Wb_in, 3145728);
  f2b_kernel<<<512, 256, 0, stream>>>(W_out, Wb_out, 1048576);

  gemm_nt<0><<<dim3(24, 64), 256, 0, stream>>>(Xb, Wb_in, b_in, 1024, nullptr, qkvt, 3072);
  vtrans_kernel<<<2048, 256, 0, stream>>>(qkvt + (size_t)2 * 128 * 65536, vt);
  qkbias_kernel<<<8192, 256, 0, stream>>>(qkvt, kde, biasD);
  attn_kernel<<<1024, 512, 0, stream>>>(qkvt, vt, biasD, vde, Ob);
  gemm_nt<1><<<dim3(8, 64), 256, 0, stream>>>(Ob, Wb_out, b_out, 1024, out, nullptr, 1024);
}